// Round 1
// baseline (474.716 us; speedup 1.0000x reference)
//
#include <hip/hip_runtime.h>
#include <math.h>

// Problem constants (B=64, N=512, F_IN=D=128, K=32, INTER=256)
#define M_ROWS 32768
#define NNODES 512
#define DDIM   128
#define KNBR   32
#define EPSBN  1e-5f

// ---------------------------------------------------------------------------
// zero the BN-stats scratch (1536 floats) — ws is poisoned 0xAA before launch
// ---------------------------------------------------------------------------
__global__ void zero_stats_kernel(float* __restrict__ p){
    int t = threadIdx.x;
    for (int i = t; i < 1536; i += 256) p[i] = 0.f;
}

// ---------------------------------------------------------------------------
// cosine similarity + top-32 per row (jax.lax.top_k tie-break: smaller index)
// one block per row i; 256 threads
// ---------------------------------------------------------------------------
__global__ __launch_bounds__(256) void topk_kernel(const float* __restrict__ emb,
                                                   int* __restrict__ topk){
    __shared__ float wi[128];
    __shared__ float cosv[512];
    __shared__ float rmax[256];
    __shared__ int   ridx[256];
    int i = blockIdx.x, tid = threadIdx.x;
    if (tid < 128) wi[tid] = emb[i*128 + tid];
    __syncthreads();
    float ni = 0.f;
    #pragma unroll 8
    for (int d = 0; d < 128; ++d) ni += wi[d]*wi[d];
    float rni = sqrtf(ni);
    for (int jj = tid; jj < 512; jj += 256){
        float dot = 0.f, nj = 0.f;
        const float* wj = emb + jj*128;
        #pragma unroll 8
        for (int d = 0; d < 128; ++d){ float w = wj[d]; dot += wi[d]*w; nj += w*w; }
        cosv[jj] = dot / (rni * sqrtf(nj));
    }
    __syncthreads();
    for (int k = 0; k < KNBR; ++k){
        float best = cosv[tid]; int bidx = tid;
        float v2 = cosv[tid+256];
        if (v2 > best){ best = v2; bidx = tid+256; }   // tie -> keep smaller idx
        rmax[tid] = best; ridx[tid] = bidx;
        __syncthreads();
        for (int s = 128; s > 0; s >>= 1){
            if (tid < s){
                float ov = rmax[tid+s]; int oi = ridx[tid+s];
                if (ov > rmax[tid] || (ov == rmax[tid] && oi < ridx[tid])){
                    rmax[tid] = ov; ridx[tid] = oi;
                }
            }
            __syncthreads();
        }
        if (tid == 0){ topk[i*KNBR + k] = ridx[0]; cosv[ridx[0]] = -1e30f; }
        __syncthreads();
    }
}

// ---------------------------------------------------------------------------
// e_i[n] = emb[n] . att_em_i ; e_j[n] = emb[n] . att_em_j   (one block per n)
// ---------------------------------------------------------------------------
__global__ __launch_bounds__(128) void embscore_kernel(const float* __restrict__ emb,
                                                       const float* __restrict__ aei,
                                                       const float* __restrict__ aej,
                                                       float* __restrict__ e_i,
                                                       float* __restrict__ e_j){
    __shared__ float si[128], sj[128];
    int n = blockIdx.x, d = threadIdx.x;
    float w = emb[n*128 + d];
    si[d] = w * aei[d];
    sj[d] = w * aej[d];
    __syncthreads();
    for (int s = 64; s > 0; s >>= 1){
        if (d < s){ si[d] += si[d+s]; sj[d] += sj[d+s]; }
        __syncthreads();
    }
    if (d == 0){ e_i[n] = si[0]; e_j[n] = sj[0]; }
}

// ---------------------------------------------------------------------------
// Generic K=128 fp32 GEMM block: out[m, cb0..cb0+63] (+bias) (+accum) with
// optional input BatchNorm(normalize+ReLU) applied at A-staging time and
// optional output column-stats (sum, sumsq) accumulation.
// grid = (256 rowgroups, Ctot/64 colblocks), 256 threads.
// LDS ~54.8 KB -> 2 blocks/CU.
// ---------------------------------------------------------------------------
template<bool NORM, bool HAS_BIAS, bool ACCUM, bool STATS>
__global__ __launch_bounds__(256) void gemm128_kernel(
    const float* __restrict__ A, int a_stride, int a_off,
    const float* __restrict__ instats, int inK,
    const float* __restrict__ gamma, const float* __restrict__ beta,
    const float* __restrict__ W, int Ctot,
    const float* __restrict__ bias,
    float* __restrict__ outp,
    float* __restrict__ outstats, int outK)
{
    __shared__ float As[32][132];     // +4 pad: bank-conflict-free 4-addr broadcast
    __shared__ float Ws[128][64];
    __shared__ float red[16][64];
    __shared__ float nsc[128], nsh[128];

    int tid = threadIdx.x;
    int cb0 = blockIdx.y * 64;

    // stage W tile once
    for (int t = tid; t < 128*64; t += 256){
        int d = t >> 6, c = t & 63;
        Ws[d][c] = W[d*Ctot + cb0 + c];
    }
    if (NORM){
        if (tid < 128){
            int dg = a_off + tid;
            float mean = instats[dg] * (1.f/32768.f);
            float var  = instats[inK + dg] * (1.f/32768.f) - mean*mean;
            float sc   = gamma[dg] / sqrtf(var + EPSBN);
            nsc[tid] = sc;
            nsh[tid] = beta[dg] - mean*sc;
        }
    }

    int tcol = tid & 15, trow = tid >> 4;
    int c0 = tcol * 4;
    float4 breg = make_float4(0.f,0.f,0.f,0.f);
    if (HAS_BIAS){
        breg.x = bias[cb0+c0+0]; breg.y = bias[cb0+c0+1];
        breg.z = bias[cb0+c0+2]; breg.w = bias[cb0+c0+3];
    }
    float s_sum[4] = {0.f,0.f,0.f,0.f}, s_ss[4] = {0.f,0.f,0.f,0.f};

    int rows_per_blk = M_ROWS / gridDim.x;          // 128
    int row0 = blockIdx.x * rows_per_blk;

    for (int chunk = 0; chunk < rows_per_blk; chunk += 32){
        __syncthreads();
        // stage (and optionally normalize+relu) 32 A rows
        for (int t = tid; t < 32*128; t += 256){
            int r = t >> 7, d = t & 127;
            float v = A[(size_t)(row0 + chunk + r)*a_stride + a_off + d];
            if (NORM) v = fmaxf(v*nsc[d] + nsh[d], 0.f);
            As[r][d] = v;
        }
        __syncthreads();

        float acc[2][4] = {{0.f,0.f,0.f,0.f},{0.f,0.f,0.f,0.f}};
        #pragma unroll 4
        for (int d = 0; d < 128; ++d){
            float a0 = As[trow][d];
            float a1 = As[trow+16][d];
            float4 w = *(const float4*)&Ws[d][c0];
            acc[0][0] += a0*w.x; acc[0][1] += a0*w.y; acc[0][2] += a0*w.z; acc[0][3] += a0*w.w;
            acc[1][0] += a1*w.x; acc[1][1] += a1*w.y; acc[1][2] += a1*w.z; acc[1][3] += a1*w.w;
        }

        #pragma unroll
        for (int rr = 0; rr < 2; ++rr){
            int grow = row0 + chunk + trow + rr*16;
            float4 res = make_float4(acc[rr][0], acc[rr][1], acc[rr][2], acc[rr][3]);
            if (HAS_BIAS){ res.x += breg.x; res.y += breg.y; res.z += breg.z; res.w += breg.w; }
            float* po = outp + (size_t)grow*Ctot + cb0 + c0;
            if (ACCUM){
                float4 old = *(const float4*)po;
                res.x += old.x; res.y += old.y; res.z += old.z; res.w += old.w;
            }
            *(float4*)po = res;
            if (STATS){
                s_sum[0] += res.x; s_ss[0] += res.x*res.x;
                s_sum[1] += res.y; s_ss[1] += res.y*res.y;
                s_sum[2] += res.z; s_ss[2] += res.z*res.z;
                s_sum[3] += res.w; s_ss[3] += res.w*res.w;
            }
        }
    }

    if (STATS){
        __syncthreads();
        #pragma unroll
        for (int j = 0; j < 4; ++j) red[trow][c0+j] = s_sum[j];
        __syncthreads();
        if (tid < 64){
            float t = 0.f;
            for (int u = 0; u < 16; ++u) t += red[u][tid];
            atomicAdd(&outstats[cb0 + tid], t);
        }
        __syncthreads();
        #pragma unroll
        for (int j = 0; j < 4; ++j) red[trow][c0+j] = s_ss[j];
        __syncthreads();
        if (tid < 64){
            float t = 0.f;
            for (int u = 0; u < 16; ++u) t += red[u][tid];
            atomicAdd(&outstats[outK + cb0 + tid], t);
        }
    }
}

// ---------------------------------------------------------------------------
// s_i[m] = x_lin[m].att_i + e_i[m%N] ; s_j analogous.  One wave per row.
// ---------------------------------------------------------------------------
__global__ __launch_bounds__(256) void score_kernel(const float* __restrict__ xlin,
                                                    const float* __restrict__ att_i,
                                                    const float* __restrict__ att_j,
                                                    const float* __restrict__ e_i,
                                                    const float* __restrict__ e_j,
                                                    float* __restrict__ s_i,
                                                    float* __restrict__ s_j){
    int gid = blockIdx.x*256 + threadIdx.x;
    int wid = gid >> 6, lane = gid & 63;
    if (wid >= M_ROWS) return;
    const float* xr = xlin + (size_t)wid*128;
    float v0 = xr[lane], v1 = xr[lane+64];
    float ai = v0*att_i[lane] + v1*att_i[lane+64];
    float aj = v0*att_j[lane] + v1*att_j[lane+64];
    for (int off = 32; off; off >>= 1){
        ai += __shfl_down(ai, off);
        aj += __shfl_down(aj, off);
    }
    if (lane == 0){
        int n = wid & 511;
        s_i[wid] = ai + e_i[n];
        s_j[wid] = aj + e_j[n];
    }
}

// ---------------------------------------------------------------------------
// attention softmax over K topk-edges + self-loop, aggregate x_lin rows.
// one block (128 threads) per node m. writes agg = sum + gnn_bias.
// ---------------------------------------------------------------------------
__global__ __launch_bounds__(128) void agg_kernel(const float* __restrict__ xlin,
                                                  const float* __restrict__ s_i,
                                                  const float* __restrict__ s_j,
                                                  const int* __restrict__ topk,
                                                  const float* __restrict__ gnn_bias,
                                                  float* __restrict__ agg){
    int m = blockIdx.x, tid = threadIdx.x;
    int b = m >> 9, i = m & 511;
    __shared__ float alpha[33];
    __shared__ int   srcs[33];
    if (tid < 33){
        int src, valid;
        if (tid < KNBR){ int j = topk[i*KNBR + tid]; src = (b << 9) + j; valid = (j != i); }
        else           { src = m; valid = 1; }
        float lg = s_i[m] + s_j[src];
        lg = (lg >= 0.f) ? lg : 0.2f*lg;            // leaky_relu 0.2
        alpha[tid] = valid ? lg : -1e9f;            // removed self-edges -> -1e9
        srcs[tid]  = src;
    }
    __syncthreads();
    if (tid == 0){
        float mx = -1e30f;
        for (int k = 0; k < 33; ++k) mx = fmaxf(mx, alpha[k]);
        float den = 0.f;
        for (int k = 0; k < 33; ++k){
            float v = alpha[k];
            float e = (v <= -1e8f) ? 0.f : expf(v - mx);
            alpha[k] = e; den += e;
        }
        float rden = 1.f / den;
        for (int k = 0; k < 33; ++k) alpha[k] *= rden;
    }
    __syncthreads();
    float acc = 0.f;
    #pragma unroll 4
    for (int k = 0; k < 33; ++k)
        acc += alpha[k] * xlin[(size_t)srcs[k]*128 + tid];
    agg[(size_t)m*128 + tid] = acc + gnn_bias[tid];
}

// ---------------------------------------------------------------------------
// column stats (sum, sumsq) of a [M, 128] matrix -> st[0..127], st[128..255]
// ---------------------------------------------------------------------------
__global__ __launch_bounds__(256) void colstats128_kernel(const float* __restrict__ X,
                                                          float* __restrict__ st){
    int tid = threadIdx.x;
    int col = tid & 127, sub = tid >> 7;
    int stream = blockIdx.x*2 + sub, nstreams = gridDim.x*2;
    float s = 0.f, q = 0.f;
    for (int m = stream; m < M_ROWS; m += nstreams){
        float v = X[(size_t)m*128 + col];
        s += v; q += v*v;
    }
    __shared__ float ls[256], lq[256];
    ls[tid] = s; lq[tid] = q;
    __syncthreads();
    if (tid < 128){
        atomicAdd(&st[tid],       ls[tid] + ls[tid+128]);
        atomicAdd(&st[128 + tid], lq[tid] + lq[tid+128]);
    }
}

// ---------------------------------------------------------------------------
// gcn = relu(bn_gnn(agg)); h = gcn * emb[m%N]; write h + accumulate h stats
// ---------------------------------------------------------------------------
__global__ __launch_bounds__(256) void gate_kernel(const float* __restrict__ agg,
                                                   const float* __restrict__ gnnstats,
                                                   const float* __restrict__ g,
                                                   const float* __restrict__ bta,
                                                   const float* __restrict__ emb,
                                                   float* __restrict__ h,
                                                   float* __restrict__ hstats){
    int tid = threadIdx.x;
    int col = tid & 127, sub = tid >> 7;
    float mean = gnnstats[col] * (1.f/32768.f);
    float var  = gnnstats[128 + col] * (1.f/32768.f) - mean*mean;
    float sc   = g[col] / sqrtf(var + EPSBN);
    float sh   = bta[col] - mean*sc;
    int stream = blockIdx.x*2 + sub, nstreams = gridDim.x*2;
    float s = 0.f, q = 0.f;
    for (int m = stream; m < M_ROWS; m += nstreams){
        float v = agg[(size_t)m*128 + col];
        v = fmaxf(v*sc + sh, 0.f);
        v *= emb[(m & 511)*128 + col];
        h[(size_t)m*128 + col] = v;
        s += v; q += v*v;
    }
    __shared__ float ls[256], lq[256];
    ls[tid] = s; lq[tid] = q;
    __syncthreads();
    if (tid < 128){
        atomicAdd(&hstats[tid],       ls[tid] + ls[tid+128]);
        atomicAdd(&hstats[128 + tid], lq[tid] + lq[tid+128]);
    }
}

// ---------------------------------------------------------------------------
// out[m] = relu(bn2(t2[m,:])) . W3 + b3    (one wave per row)
// ---------------------------------------------------------------------------
__global__ __launch_bounds__(256) void final_kernel(const float* __restrict__ t2,
                                                    const float* __restrict__ st,
                                                    const float* __restrict__ g,
                                                    const float* __restrict__ bta,
                                                    const float* __restrict__ W3,
                                                    const float* __restrict__ b3,
                                                    float* __restrict__ outp){
    int gid = blockIdx.x*256 + threadIdx.x;
    int wid = gid >> 6, lane = gid & 63;
    if (wid >= M_ROWS) return;
    const float* row = t2 + (size_t)wid*256;
    float acc = 0.f;
    #pragma unroll
    for (int u = 0; u < 4; ++u){
        int c = lane + u*64;
        float mean = st[c] * (1.f/32768.f);
        float var  = st[256 + c] * (1.f/32768.f) - mean*mean;
        float v = (row[c] - mean) * (g[c] / sqrtf(var + EPSBN)) + bta[c];
        v = fmaxf(v, 0.f);
        acc += v * W3[c];
    }
    for (int off = 32; off; off >>= 1) acc += __shfl_down(acc, off);
    if (lane == 0) outp[wid] = acc + b3[0];
}

// ---------------------------------------------------------------------------
extern "C" void kernel_launch(void* const* d_in, const int* in_sizes, int n_in,
                              void* d_out, int out_size, void* d_ws, size_t ws_size,
                              hipStream_t stream)
{
    (void)in_sizes; (void)n_in; (void)out_size; (void)ws_size;
    const float* data   = (const float*)d_in[0];
    const float* emb    = (const float*)d_in[1];
    const float* lin_W  = (const float*)d_in[2];
    const float* att_i  = (const float*)d_in[3];
    const float* att_j  = (const float*)d_in[4];
    const float* aem_i  = (const float*)d_in[5];
    const float* aem_j  = (const float*)d_in[6];
    const float* gnn_bias = (const float*)d_in[7];
    const float* gnn_g  = (const float*)d_in[8];
    const float* gnn_b  = (const float*)d_in[9];
    const float* bno_g  = (const float*)d_in[10];
    const float* bno_b  = (const float*)d_in[11];
    const float* W1     = (const float*)d_in[12];
    const float* b1     = (const float*)d_in[13];
    const float* bn1_g  = (const float*)d_in[14];
    const float* bn1_b  = (const float*)d_in[15];
    const float* W2     = (const float*)d_in[16];
    const float* b2     = (const float*)d_in[17];
    const float* bn2_g  = (const float*)d_in[18];
    const float* bn2_b  = (const float*)d_in[19];
    const float* W3     = (const float*)d_in[20];
    const float* b3     = (const float*)d_in[21];
    float* outp = (float*)d_out;
    char*  ws   = (char*)d_ws;

    // workspace layout (bytes)
    int*   topk     = (int*)ws;                         // 64 KB
    float* e_i      = (float*)(ws + 65536);
    float* e_j      = (float*)(ws + 67584);
    float* s_i      = (float*)(ws + 69632);             // 128 KB
    float* s_j      = (float*)(ws + 200704);            // 128 KB
    float* stats    = (float*)(ws + 331776);            // 1536 floats
    float* gnnstats = stats;                            // [256]
    float* hstats   = stats + 256;                      // [256]
    float* bn1stats = stats + 512;                      // [512]
    float* bn2stats = stats + 1024;                     // [512]
    float* region0  = (float*)(ws + 524288);            // 32 MB
    float* xlin     = region0;                          // 16 MB
    float* agg      = region0 + 4194304;                // 16 MB
    float* t1       = region0;                          // 32 MB (aliases xlin+agg, both dead)
    float* region1  = (float*)(ws + 524288 + 33554432); // 32 MB
    float* h        = region1;                          // 16 MB
    float* t2       = region1;                          // 32 MB (aliases h, dead by then)

    zero_stats_kernel<<<1, 256, 0, stream>>>(stats);
    topk_kernel<<<NNODES, 256, 0, stream>>>(emb, topk);
    embscore_kernel<<<NNODES, 128, 0, stream>>>(emb, aem_i, aem_j, e_i, e_j);

    // x_lin = data @ lin_W          [32768,128]x[128,128]
    gemm128_kernel<false,false,false,false><<<dim3(256,2), 256, 0, stream>>>(
        data, 128, 0, nullptr, 0, nullptr, nullptr, lin_W, 128, nullptr, xlin, nullptr, 0);

    score_kernel<<<M_ROWS/4, 256, 0, stream>>>(xlin, att_i, att_j, e_i, e_j, s_i, s_j);
    agg_kernel<<<M_ROWS, 128, 0, stream>>>(xlin, s_i, s_j, topk, gnn_bias, agg);
    colstats128_kernel<<<256, 256, 0, stream>>>(agg, gnnstats);
    gate_kernel<<<256, 256, 0, stream>>>(agg, gnnstats, gnn_g, gnn_b, emb, h, hstats);

    // t1 = relu(bn_out(h)) @ W1 + b1   (+ bn1 stats)
    gemm128_kernel<true,true,false,true><<<dim3(256,4), 256, 0, stream>>>(
        h, 128, 0, hstats, 128, bno_g, bno_b, W1, 256, b1, t1, bn1stats, 256);

    // t2 = relu(bn1(t1))[:, :128] @ W2[:128,:] + b2
    gemm128_kernel<true,true,false,false><<<dim3(256,4), 256, 0, stream>>>(
        t1, 256, 0, bn1stats, 256, bn1_g, bn1_b, W2, 256, b2, t2, nullptr, 0);
    // t2 += relu(bn1(t1))[:, 128:] @ W2[128:,:]   (+ bn2 stats)
    gemm128_kernel<true,false,true,true><<<dim3(256,4), 256, 0, stream>>>(
        t1, 256, 128, bn1stats, 256, bn1_g, bn1_b, W2 + 128*256, 256, nullptr, t2, bn2stats, 256);

    final_kernel<<<M_ROWS/4, 256, 0, stream>>>(t2, bn2stats, bn2_g, bn2_b, W3, b3, outp);
}

// Round 2
// 318.850 us; speedup vs baseline: 1.4888x; 1.4888x over previous
//
#include <hip/hip_runtime.h>
#include <math.h>

// Problem constants (B=64, N=512, F_IN=D=128, K=32, INTER=256)
#define M_ROWS 32768
#define NNODES 512
#define KNBR   32
#define EPSBN  1e-5f

typedef __bf16 bf16x8 __attribute__((ext_vector_type(8)));
typedef __bf16 bf16x4 __attribute__((ext_vector_type(4)));
typedef float  f32x4  __attribute__((ext_vector_type(4)));

// ---------------------------------------------------------------------------
// zero the BN-stats scratch (1536 floats)
// ---------------------------------------------------------------------------
__global__ void zero_stats_kernel(float* __restrict__ p){
    int t = threadIdx.x;
    for (int i = t; i < 1536; i += 256) p[i] = 0.f;
}

// ---------------------------------------------------------------------------
// cosine similarity + top-32 per row (tie-break: smaller index).
// cos by 256 threads; selection by wave 0 only (shuffle argmax, no barriers).
// ---------------------------------------------------------------------------
__global__ __launch_bounds__(256) void topk_kernel(const float* __restrict__ emb,
                                                   int* __restrict__ topk){
    __shared__ float wi[128];
    __shared__ float cosv[512];
    int i = blockIdx.x, tid = threadIdx.x;
    if (tid < 128) wi[tid] = emb[i*128 + tid];
    __syncthreads();
    float ni = 0.f;
    #pragma unroll 8
    for (int d = 0; d < 128; ++d) ni += wi[d]*wi[d];
    float rni = sqrtf(ni);
    for (int jj = tid; jj < 512; jj += 256){
        const float4* wj4 = (const float4*)(emb + jj*128);
        float dot = 0.f, nj = 0.f;
        #pragma unroll 8
        for (int d4 = 0; d4 < 32; ++d4){
            float4 w = wj4[d4];
            dot += wi[4*d4+0]*w.x + wi[4*d4+1]*w.y + wi[4*d4+2]*w.z + wi[4*d4+3]*w.w;
            nj  += w.x*w.x + w.y*w.y + w.z*w.z + w.w*w.w;
        }
        cosv[jj] = dot / (rni * sqrtf(nj));
    }
    __syncthreads();
    if (tid < 64){
        int lane = tid;
        float v[8];
        #pragma unroll
        for (int jj = 0; jj < 8; ++jj) v[jj] = cosv[lane + 64*jj];
        for (int k = 0; k < KNBR; ++k){
            // local argmax (ascending scan keeps smallest local index on ties)
            float bv = v[0]; int bj = 0;
            #pragma unroll
            for (int jj = 1; jj < 8; ++jj) if (v[jj] > bv){ bv = v[jj]; bj = jj; }
            int bi = lane + 64*bj;
            // wave argmax with (value desc, index asc) ordering
            #pragma unroll
            for (int mask = 1; mask < 64; mask <<= 1){
                float ov = __shfl_xor(bv, mask);
                int   oi = __shfl_xor(bi, mask);
                if (ov > bv || (ov == bv && oi < bi)){ bv = ov; bi = oi; }
            }
            if (lane == 0) topk[i*KNBR + k] = bi;
            if ((bi & 63) == lane){
                int jj = bi >> 6;
                #pragma unroll
                for (int j2 = 0; j2 < 8; ++j2) if (j2 == jj) v[j2] = -2e30f;
            }
        }
    }
}

// ---------------------------------------------------------------------------
// e_i[n] = emb[n] . att_em_i ; e_j[n] = emb[n] . att_em_j
// ---------------------------------------------------------------------------
__global__ __launch_bounds__(128) void embscore_kernel(const float* __restrict__ emb,
                                                       const float* __restrict__ aei,
                                                       const float* __restrict__ aej,
                                                       float* __restrict__ e_i,
                                                       float* __restrict__ e_j){
    __shared__ float si[128], sj[128];
    int n = blockIdx.x, d = threadIdx.x;
    float w = emb[n*128 + d];
    si[d] = w * aei[d];
    sj[d] = w * aej[d];
    __syncthreads();
    for (int s = 64; s > 0; s >>= 1){
        if (d < s){ si[d] += si[d+s]; sj[d] += sj[d+s]; }
        __syncthreads();
    }
    if (d == 0){ e_i[n] = si[0]; e_j[n] = sj[0]; }
}

// ---------------------------------------------------------------------------
// bf16 MFMA GEMM: out[M x Ctot] = act(A[M x Ktot]) @ W[Ktot x Ctot] (+bias)
//   NORM : A-staging applies BatchNorm(instats)+ReLU before bf16 convert
//   STATS: accumulate column sum/sumsq of the fp32 outputs into outstats
// block = 256 thr (4 waves), tile 128 rows x 64 cols, K chunked by 128.
// mfma_f32_16x16x32_bf16; A frag [m=lane&15][k=(lane>>4)*8+j];
// B frag [k=(lane>>4)*8+j][n=lane&15]; C/D col=lane&15, row=(lane>>4)*4+reg.
// LDS ~52.7 KB -> 3 blocks/CU.
// ---------------------------------------------------------------------------
template<bool NORM, bool HAS_BIAS, bool STATS>
__global__ __launch_bounds__(256) void gemm_mfma_kernel(
    const float* __restrict__ A, int a_stride, int Ktot,
    const float* __restrict__ instats,
    const float* __restrict__ gamma, const float* __restrict__ beta,
    const float* __restrict__ W, int Ctot,
    const float* __restrict__ bias,
    float* __restrict__ outp,
    float* __restrict__ outstats, int outK)
{
    __shared__ __align__(16) __bf16 As[128][136];   // 272 B row stride (16B mult)
    __shared__ __align__(16) __bf16 Bp[16][64][8];  // B packed in frag order
    __shared__ float nsc[128], nsh[128];
    __shared__ float statS[64], statQ[64];

    int tid  = threadIdx.x;
    int lane = tid & 63, wv = tid >> 6;
    int mrow = lane & 15, q = lane >> 4;
    int cb0  = blockIdx.y * 64;
    int row0 = blockIdx.x * 128;

    f32x4 acc[2][4];
    #pragma unroll
    for (int rt = 0; rt < 2; ++rt)
        #pragma unroll
        for (int ct = 0; ct < 4; ++ct)
            acc[rt][ct] = (f32x4){0.f,0.f,0.f,0.f};

    for (int kc = 0; kc < Ktot; kc += 128){
        if (NORM && tid < 128){
            int f = kc + tid;
            float mean = instats[f] * (1.f/32768.f);
            float var  = instats[Ktot + f] * (1.f/32768.f) - mean*mean;
            float sc   = gamma[f] / sqrtf(var + EPSBN);
            nsc[tid] = sc;
            nsh[tid] = beta[f] - mean*sc;
        }
        __syncthreads();   // nsc ready; previous chunk's reads done

        // stage A (BN+ReLU fused), fp32 -> bf16
        for (int t = tid; t < 4096; t += 256){
            int r = t >> 5, c4 = (t & 31) << 2;
            float4 av = *(const float4*)&A[(size_t)(row0 + r)*a_stride + kc + c4];
            if (NORM){
                av.x = fmaxf(av.x*nsc[c4+0] + nsh[c4+0], 0.f);
                av.y = fmaxf(av.y*nsc[c4+1] + nsh[c4+1], 0.f);
                av.z = fmaxf(av.z*nsc[c4+2] + nsh[c4+2], 0.f);
                av.w = fmaxf(av.w*nsc[c4+3] + nsh[c4+3], 0.f);
            }
            bf16x4 pk;
            pk[0] = (__bf16)av.x; pk[1] = (__bf16)av.y;
            pk[2] = (__bf16)av.z; pk[3] = (__bf16)av.w;
            *(bf16x4*)&As[r][c4] = pk;
        }
        // stage W tile packed: Bp[kg][c][j] = W[kc+kg*8+j][cb0+c]
        for (int t = tid; t < 1024; t += 256){
            int kg = t >> 6, c = t & 63;
            bf16x8 pk;
            #pragma unroll
            for (int j = 0; j < 8; ++j)
                pk[j] = (__bf16)W[(size_t)(kc + kg*8 + j)*Ctot + cb0 + c];
            *(bf16x8*)&Bp[kg][c][0] = pk;
        }
        __syncthreads();

        #pragma unroll
        for (int ks = 0; ks < 4; ++ks){
            bf16x8 a0 = *(const bf16x8*)&As[wv*32      + mrow][ks*32 + q*8];
            bf16x8 a1 = *(const bf16x8*)&As[wv*32 + 16 + mrow][ks*32 + q*8];
            #pragma unroll
            for (int ct = 0; ct < 4; ++ct){
                bf16x8 bb = *(const bf16x8*)&Bp[ks*4 + q][ct*16 + mrow][0];
                acc[0][ct] = __builtin_amdgcn_mfma_f32_16x16x32_bf16(a0, bb, acc[0][ct], 0, 0, 0);
                acc[1][ct] = __builtin_amdgcn_mfma_f32_16x16x32_bf16(a1, bb, acc[1][ct], 0, 0, 0);
            }
        }
        __syncthreads();
    }

    if (STATS){
        if (tid < 64){ statS[tid] = 0.f; statQ[tid] = 0.f; }
        __syncthreads();
    }

    // epilogue: bias + store + (stats)
    float cs[4] = {0.f,0.f,0.f,0.f}, cq[4] = {0.f,0.f,0.f,0.f};
    #pragma unroll
    for (int ct = 0; ct < 4; ++ct){
        int col = cb0 + ct*16 + mrow;
        float bv = HAS_BIAS ? bias[col] : 0.f;
        #pragma unroll
        for (int rt = 0; rt < 2; ++rt){
            #pragma unroll
            for (int reg = 0; reg < 4; ++reg){
                int row = row0 + wv*32 + rt*16 + q*4 + reg;
                float v = acc[rt][ct][reg] + bv;
                outp[(size_t)row*Ctot + col] = v;
                if (STATS){ cs[ct] += v; cq[ct] += v*v; }
            }
        }
    }
    if (STATS){
        #pragma unroll
        for (int ct = 0; ct < 4; ++ct){
            float s = cs[ct]; s += __shfl_xor(s, 16); s += __shfl_xor(s, 32);
            float qq = cq[ct]; qq += __shfl_xor(qq, 16); qq += __shfl_xor(qq, 32);
            if (q == 0){
                atomicAdd(&statS[ct*16 + mrow], s);
                atomicAdd(&statQ[ct*16 + mrow], qq);
            }
        }
        __syncthreads();
        if (tid < 64){
            atomicAdd(&outstats[cb0 + tid],        statS[tid]);
            atomicAdd(&outstats[outK + cb0 + tid], statQ[tid]);
        }
    }
}

// ---------------------------------------------------------------------------
// s_i[m] = x_lin[m].att_i + e_i[m%N] ; s_j analogous.  One wave per row.
// ---------------------------------------------------------------------------
__global__ __launch_bounds__(256) void score_kernel(const float2* __restrict__ xlin2,
                                                    const float2* __restrict__ att_i2,
                                                    const float2* __restrict__ att_j2,
                                                    const float* __restrict__ e_i,
                                                    const float* __restrict__ e_j,
                                                    float* __restrict__ s_i,
                                                    float* __restrict__ s_j){
    int gid = blockIdx.x*256 + threadIdx.x;
    int wid = gid >> 6, lane = gid & 63;
    float2 v  = xlin2[(size_t)wid*64 + lane];
    float2 ai2 = att_i2[lane], aj2 = att_j2[lane];
    float ai = v.x*ai2.x + v.y*ai2.y;
    float aj = v.x*aj2.x + v.y*aj2.y;
    for (int off = 32; off; off >>= 1){
        ai += __shfl_down(ai, off);
        aj += __shfl_down(aj, off);
    }
    if (lane == 0){
        int n = wid & 511;
        s_i[wid] = ai + e_i[n];
        s_j[wid] = aj + e_j[n];
    }
}

// ---------------------------------------------------------------------------
// attention softmax + aggregation: ONE WAVE per node, shuffle softmax,
// float2 gathers (one 512 B row per load instruction).
// ---------------------------------------------------------------------------
__global__ __launch_bounds__(256) void agg_kernel(const float2* __restrict__ xlin2,
                                                  const float* __restrict__ s_i,
                                                  const float* __restrict__ s_j,
                                                  const int* __restrict__ topk,
                                                  const float2* __restrict__ gnn_bias2,
                                                  float2* __restrict__ agg2){
    int gid  = blockIdx.x*256 + threadIdx.x;
    int m    = gid >> 6, lane = gid & 63;
    int b = m >> 9, i = m & 511;
    int src; bool valid;
    if (lane < KNBR){ int j = topk[i*KNBR + lane]; src = (b << 9) + j; valid = (j != i); }
    else            { src = m; valid = (lane == KNBR); }
    float l = s_i[m] + s_j[src];
    l = (l >= 0.f) ? l : 0.2f*l;                 // leaky_relu 0.2
    l = valid ? l : -1e30f;
    float mx = l;
    #pragma unroll
    for (int mask = 1; mask < 64; mask <<= 1) mx = fmaxf(mx, __shfl_xor(mx, mask));
    float e = valid ? __expf(l - mx) : 0.f;
    float den = e;
    #pragma unroll
    for (int mask = 1; mask < 64; mask <<= 1) den += __shfl_xor(den, mask);
    float alpha = e / den;

    float2 acc = make_float2(0.f, 0.f);
    #pragma unroll 4
    for (int k = 0; k < 33; ++k){
        float a = __shfl(alpha, k);
        int   s = __shfl(src, k);
        float2 v = xlin2[(size_t)s*64 + lane];
        acc.x += a*v.x; acc.y += a*v.y;
    }
    float2 bv = gnn_bias2[lane];
    acc.x += bv.x; acc.y += bv.y;
    agg2[(size_t)m*64 + lane] = acc;
}

// ---------------------------------------------------------------------------
// column stats (sum, sumsq) of a [M, 128] matrix -> st[0..127], st[128..255]
// ---------------------------------------------------------------------------
__global__ __launch_bounds__(256) void colstats128_kernel(const float* __restrict__ X,
                                                          float* __restrict__ st){
    int tid = threadIdx.x;
    int col = tid & 127, sub = tid >> 7;
    int stream = blockIdx.x*2 + sub, nstreams = gridDim.x*2;
    float s = 0.f, q = 0.f;
    for (int m = stream; m < M_ROWS; m += nstreams){
        float v = X[(size_t)m*128 + col];
        s += v; q += v*v;
    }
    __shared__ float ls[256], lq[256];
    ls[tid] = s; lq[tid] = q;
    __syncthreads();
    if (tid < 128){
        atomicAdd(&st[tid],       ls[tid] + ls[tid+128]);
        atomicAdd(&st[128 + tid], lq[tid] + lq[tid+128]);
    }
}

// ---------------------------------------------------------------------------
// gcn = relu(bn_gnn(agg)); h = gcn * emb[m%N]; write h + accumulate h stats
// ---------------------------------------------------------------------------
__global__ __launch_bounds__(256) void gate_kernel(const float* __restrict__ agg,
                                                   const float* __restrict__ gnnstats,
                                                   const float* __restrict__ g,
                                                   const float* __restrict__ bta,
                                                   const float* __restrict__ emb,
                                                   float* __restrict__ h,
                                                   float* __restrict__ hstats){
    int tid = threadIdx.x;
    int col = tid & 127, sub = tid >> 7;
    float mean = gnnstats[col] * (1.f/32768.f);
    float var  = gnnstats[128 + col] * (1.f/32768.f) - mean*mean;
    float sc   = g[col] / sqrtf(var + EPSBN);
    float sh   = bta[col] - mean*sc;
    int stream = blockIdx.x*2 + sub, nstreams = gridDim.x*2;
    float s = 0.f, q = 0.f;
    for (int m = stream; m < M_ROWS; m += nstreams){
        float v = agg[(size_t)m*128 + col];
        v = fmaxf(v*sc + sh, 0.f);
        v *= emb[(m & 511)*128 + col];
        h[(size_t)m*128 + col] = v;
        s += v; q += v*v;
    }
    __shared__ float ls[256], lq[256];
    ls[tid] = s; lq[tid] = q;
    __syncthreads();
    if (tid < 128){
        atomicAdd(&hstats[tid],       ls[tid] + ls[tid+128]);
        atomicAdd(&hstats[128 + tid], lq[tid] + lq[tid+128]);
    }
}

// ---------------------------------------------------------------------------
// out[m] = relu(bn2(t2[m,:])) . W3 + b3    (one wave per row)
// ---------------------------------------------------------------------------
__global__ __launch_bounds__(256) void final_kernel(const float* __restrict__ t2,
                                                    const float* __restrict__ st,
                                                    const float* __restrict__ g,
                                                    const float* __restrict__ bta,
                                                    const float* __restrict__ W3,
                                                    const float* __restrict__ b3,
                                                    float* __restrict__ outp){
    int gid = blockIdx.x*256 + threadIdx.x;
    int wid = gid >> 6, lane = gid & 63;
    const float* row = t2 + (size_t)wid*256;
    float acc = 0.f;
    #pragma unroll
    for (int u = 0; u < 4; ++u){
        int c = lane + u*64;
        float mean = st[c] * (1.f/32768.f);
        float var  = st[256 + c] * (1.f/32768.f) - mean*mean;
        float v = (row[c] - mean) * (g[c] / sqrtf(var + EPSBN)) + bta[c];
        v = fmaxf(v, 0.f);
        acc += v * W3[c];
    }
    for (int off = 32; off; off >>= 1) acc += __shfl_down(acc, off);
    if (lane == 0) outp[wid] = acc + b3[0];
}

// ---------------------------------------------------------------------------
extern "C" void kernel_launch(void* const* d_in, const int* in_sizes, int n_in,
                              void* d_out, int out_size, void* d_ws, size_t ws_size,
                              hipStream_t stream)
{
    (void)in_sizes; (void)n_in; (void)out_size; (void)ws_size;
    const float* data   = (const float*)d_in[0];
    const float* emb    = (const float*)d_in[1];
    const float* lin_W  = (const float*)d_in[2];
    const float* att_i  = (const float*)d_in[3];
    const float* att_j  = (const float*)d_in[4];
    const float* aem_i  = (const float*)d_in[5];
    const float* aem_j  = (const float*)d_in[6];
    const float* gnn_bias = (const float*)d_in[7];
    const float* gnn_g  = (const float*)d_in[8];
    const float* gnn_b  = (const float*)d_in[9];
    const float* bno_g  = (const float*)d_in[10];
    const float* bno_b  = (const float*)d_in[11];
    const float* W1     = (const float*)d_in[12];
    const float* b1     = (const float*)d_in[13];
    const float* bn1_g  = (const float*)d_in[14];
    const float* bn1_b  = (const float*)d_in[15];
    const float* W2     = (const float*)d_in[16];
    const float* b2     = (const float*)d_in[17];
    const float* bn2_g  = (const float*)d_in[18];
    const float* bn2_b  = (const float*)d_in[19];
    const float* W3     = (const float*)d_in[20];
    const float* b3     = (const float*)d_in[21];
    float* outp = (float*)d_out;
    char*  ws   = (char*)d_ws;

    // workspace layout (bytes)
    int*   topk     = (int*)ws;                         // 64 KB
    float* e_i      = (float*)(ws + 65536);
    float* e_j      = (float*)(ws + 67584);
    float* s_i      = (float*)(ws + 69632);             // 128 KB
    float* s_j      = (float*)(ws + 200704);            // 128 KB
    float* stats    = (float*)(ws + 331776);            // 1536 floats
    float* gnnstats = stats;                            // [256]
    float* hstats   = stats + 256;                      // [256]
    float* bn1stats = stats + 512;                      // [512]
    float* bn2stats = stats + 1024;                     // [512]
    float* region0  = (float*)(ws + 524288);            // 32 MB
    float* xlin     = region0;                          // 16 MB
    float* agg      = region0 + 4194304;                // 16 MB
    float* t1       = region0;                          // 32 MB (aliases xlin+agg, both dead)
    float* region1  = (float*)(ws + 524288 + 33554432); // 32 MB
    float* h        = region1;                          // 16 MB
    float* t2       = region1;                          // 32 MB (aliases h, dead by then)

    zero_stats_kernel<<<1, 256, 0, stream>>>(stats);
    topk_kernel<<<NNODES, 256, 0, stream>>>(emb, topk);
    embscore_kernel<<<NNODES, 128, 0, stream>>>(emb, aem_i, aem_j, e_i, e_j);

    // x_lin = data @ lin_W          [32768,128]x[128,128]  (bf16 MFMA)
    gemm_mfma_kernel<false,false,false><<<dim3(256,2), 256, 0, stream>>>(
        data, 128, 128, nullptr, nullptr, nullptr, lin_W, 128, nullptr, xlin, nullptr, 0);

    score_kernel<<<M_ROWS/4, 256, 0, stream>>>((const float2*)xlin, (const float2*)att_i,
                                               (const float2*)att_j, e_i, e_j, s_i, s_j);
    agg_kernel<<<M_ROWS/4, 256, 0, stream>>>((const float2*)xlin, s_i, s_j, topk,
                                             (const float2*)gnn_bias, (float2*)agg);
    colstats128_kernel<<<256, 256, 0, stream>>>(agg, gnnstats);
    gate_kernel<<<256, 256, 0, stream>>>(agg, gnnstats, gnn_g, gnn_b, emb, h, hstats);

    // t1 = relu(bn_out(h)) @ W1 + b1   (+ bn1 stats)
    gemm_mfma_kernel<true,true,true><<<dim3(256,4), 256, 0, stream>>>(
        h, 128, 128, hstats, bno_g, bno_b, W1, 256, b1, t1, bn1stats, 256);

    // t2 = relu(bn1(t1)) @ W2 + b2     (K=256 chunked in-kernel, + bn2 stats)
    gemm_mfma_kernel<true,true,true><<<dim3(256,4), 256, 0, stream>>>(
        t1, 256, 256, bn1stats, bn1_g, bn1_b, W2, 256, b2, t2, bn2stats, 256);

    final_kernel<<<M_ROWS/4, 256, 0, stream>>>(t2, bn2stats, bn2_g, bn2_b, W3, b3, outp);
}

// Round 3
// 264.975 us; speedup vs baseline: 1.7915x; 1.2033x over previous
//
#include <hip/hip_runtime.h>
#include <math.h>

// Problem constants (B=64, N=512, F_IN=D=128, K=32, INTER=256)
#define M_ROWS 32768
#define NNODES 512
#define KNBR   32
#define EPSBN  1e-5f

typedef __bf16 bf16x8 __attribute__((ext_vector_type(8)));
typedef __bf16 bf16x4 __attribute__((ext_vector_type(4)));
typedef __bf16 bf16x2 __attribute__((ext_vector_type(2)));
typedef float  f32x4  __attribute__((ext_vector_type(4)));

#if defined(__has_builtin)
#if __has_builtin(__builtin_amdgcn_global_load_lds)
#define HAVE_GLL 1
#endif
#endif

// async global->LDS 16B: LDS dst must be wave-uniform base + lane*16
__device__ __forceinline__ void async_ld16(void* lds, const void* g){
#ifdef HAVE_GLL
    __builtin_amdgcn_global_load_lds((__attribute__((address_space(1))) void*)(g),
                                     (__attribute__((address_space(3))) void*)(lds),
                                     16, 0, 0);
#else
    *(bf16x8*)lds = *(const bf16x8*)g;
#endif
}

// ---------------------------------------------------------------------------
// zero BN-stats scratch (1536 floats)
// ---------------------------------------------------------------------------
__global__ void zero_stats_kernel(float* __restrict__ p){
    int t = threadIdx.x;
    for (int i = t; i < 1536; i += 256) p[i] = 0.f;
}

// ---------------------------------------------------------------------------
// pack lin_W/W1/W2 fp32 -> bf16 in MFMA B-fragment granule order:
// Wp[(kg*C + c)*8 + j] = W[(kg*8+j)*C + c]
// total granules: 2048 (lin_W) + 4096 (W1) + 8192 (W2) = 14336 -> 56 blocks
// ---------------------------------------------------------------------------
__global__ __launch_bounds__(256) void packw_kernel(const float* __restrict__ lin_W,
                                                    const float* __restrict__ W1,
                                                    const float* __restrict__ W2,
                                                    __bf16* __restrict__ Wp0,
                                                    __bf16* __restrict__ Wp1,
                                                    __bf16* __restrict__ Wp2){
    int gidx = blockIdx.x*256 + threadIdx.x;      // 0..14335
    const float* W; __bf16* o; int C, lg;
    if (gidx < 2048)      { W = lin_W; o = Wp0; C = 128; lg = gidx; }
    else if (gidx < 6144) { W = W1;    o = Wp1; C = 256; lg = gidx - 2048; }
    else                  { W = W2;    o = Wp2; C = 256; lg = gidx - 6144; }
    int kg = (C == 128) ? (lg >> 7) : (lg >> 8);
    int c  = lg & (C - 1);
    bf16x8 pk;
    #pragma unroll
    for (int j = 0; j < 8; ++j) pk[j] = (__bf16)W[(size_t)(kg*8 + j)*C + c];
    *(bf16x8*)&o[(size_t)lg*8] = pk;
}

// ---------------------------------------------------------------------------
// cosine similarity + top-32 per row (tie-break: smaller index)
// ---------------------------------------------------------------------------
__global__ __launch_bounds__(256) void topk_kernel(const float* __restrict__ emb,
                                                   int* __restrict__ topk){
    __shared__ float wi[128];
    __shared__ float cosv[512];
    int i = blockIdx.x, tid = threadIdx.x;
    if (tid < 128) wi[tid] = emb[i*128 + tid];
    __syncthreads();
    float ni = 0.f;
    #pragma unroll 8
    for (int d = 0; d < 128; ++d) ni += wi[d]*wi[d];
    float rni = sqrtf(ni);
    for (int jj = tid; jj < 512; jj += 256){
        const float4* wj4 = (const float4*)(emb + jj*128);
        float dot = 0.f, nj = 0.f;
        #pragma unroll 8
        for (int d4 = 0; d4 < 32; ++d4){
            float4 w = wj4[d4];
            dot += wi[4*d4+0]*w.x + wi[4*d4+1]*w.y + wi[4*d4+2]*w.z + wi[4*d4+3]*w.w;
            nj  += w.x*w.x + w.y*w.y + w.z*w.z + w.w*w.w;
        }
        cosv[jj] = dot / (rni * sqrtf(nj));
    }
    __syncthreads();
    if (tid < 64){
        int lane = tid;
        float v[8];
        #pragma unroll
        for (int jj = 0; jj < 8; ++jj) v[jj] = cosv[lane + 64*jj];
        for (int k = 0; k < KNBR; ++k){
            float bv = v[0]; int bj = 0;
            #pragma unroll
            for (int jj = 1; jj < 8; ++jj) if (v[jj] > bv){ bv = v[jj]; bj = jj; }
            int bi = lane + 64*bj;
            #pragma unroll
            for (int mask = 1; mask < 64; mask <<= 1){
                float ov = __shfl_xor(bv, mask);
                int   oi = __shfl_xor(bi, mask);
                if (ov > bv || (ov == bv && oi < bi)){ bv = ov; bi = oi; }
            }
            if (lane == 0) topk[i*KNBR + k] = bi;
            if ((bi & 63) == lane){
                int jj = bi >> 6;
                #pragma unroll
                for (int j2 = 0; j2 < 8; ++j2) if (j2 == jj) v[j2] = -2e30f;
            }
        }
    }
}

// ---------------------------------------------------------------------------
// e_i[n] = emb[n].att_em_i ; e_j[n] = emb[n].att_em_j
// ---------------------------------------------------------------------------
__global__ __launch_bounds__(128) void embscore_kernel(const float* __restrict__ emb,
                                                       const float* __restrict__ aei,
                                                       const float* __restrict__ aej,
                                                       float* __restrict__ e_i,
                                                       float* __restrict__ e_j){
    __shared__ float si[128], sj[128];
    int n = blockIdx.x, d = threadIdx.x;
    float w = emb[n*128 + d];
    si[d] = w * aei[d];
    sj[d] = w * aej[d];
    __syncthreads();
    for (int s = 64; s > 0; s >>= 1){
        if (d < s){ si[d] += si[d+s]; sj[d] += sj[d+s]; }
        __syncthreads();
    }
    if (d == 0){ e_i[n] = si[0]; e_j[n] = sj[0]; }
}

// ---------------------------------------------------------------------------
// bf16 MFMA GEMM v3: out[M x Ctot](bf16) = act(A) @ W (+bias)
//  - tile RT*64 rows x 128 cols, 4 waves, K chunked by 128
//  - B pre-packed in fragment order, staged via global_load_lds (16B granules)
//  - A staged through regs (BN+ReLU fused when NORM), bf16 in LDS
//  - STATS: column sum/sumsq of the (rounded) outputs into outstats
// LDS: RT=2 -> ~68 KB (2 blocks/CU); RT=1 -> ~51 KB (3 blocks/CU)
// ---------------------------------------------------------------------------
template<bool ABF16, bool NORM, bool HAS_BIAS, bool STATS, int RT>
__global__ __launch_bounds__(256) void gemm_kernel(
    const void* __restrict__ Av, int a_stride, int Ktot,
    const float* __restrict__ instats,
    const float* __restrict__ gamma, const float* __restrict__ beta,
    const __bf16* __restrict__ Wp, int Ctot,
    const float* __restrict__ bias,
    __bf16* __restrict__ outp,
    float* __restrict__ outstats, int outK)
{
    constexpr int ROWS = RT*64;
    __shared__ __align__(16) __bf16 As[ROWS][136];   // 272B stride: pad balances banks
    __shared__ __align__(16) __bf16 Bp[16][128][8];  // frag-order granules
    __shared__ float nsc[128], nsh[128];
    __shared__ float statS[128], statQ[128];

    int tid  = threadIdx.x;
    int lane = tid & 63, wv = tid >> 6;
    int mrow = lane & 15, q = lane >> 4;
    int cb0  = blockIdx.y * 128;
    int row0 = blockIdx.x * ROWS;

    f32x4 acc[RT][8];
    #pragma unroll
    for (int rt = 0; rt < RT; ++rt)
        #pragma unroll
        for (int ct = 0; ct < 8; ++ct)
            acc[rt][ct] = (f32x4){0.f,0.f,0.f,0.f};

    for (int kc = 0; kc < Ktot; kc += 128){
        if (NORM && tid < 128){
            int f = kc + tid;
            float mean = instats[f] * (1.f/32768.f);
            float var  = instats[Ktot + f] * (1.f/32768.f) - mean*mean;
            float sc   = gamma[f] / sqrtf(var + EPSBN);
            nsc[tid] = sc;
            nsh[tid] = beta[f] - mean*sc;
        }
        __syncthreads();   // prev chunk's MFMA reads done; nsc visible

        // B: async 16B granules straight into LDS (frag order, lane-contiguous)
        int kg0 = kc >> 3;
        #pragma unroll
        for (int i = 0; i < 8; ++i){
            int p = tid + i*256;                       // 0..2047
            const __bf16* src = Wp + ((size_t)(kg0 + (p>>7))*Ctot + cb0 + (p&127))*8;
            async_ld16((__bf16*)Bp + (size_t)p*8, src);
        }
        // A: through regs (transform), bf16 into LDS
        if (ABF16){
            const __bf16* A = (const __bf16*)Av;
            #pragma unroll
            for (int i = 0; i < ROWS/16; ++i){
                int p = tid + i*256;
                int r = p >> 4, c8 = p & 15;
                bf16x8 v = *(const bf16x8*)&A[(size_t)(row0 + r)*a_stride + kc + c8*8];
                if (NORM){
                    bf16x8 o;
                    #pragma unroll
                    for (int j = 0; j < 8; ++j){
                        int f = c8*8 + j;
                        o[j] = (__bf16)fmaxf((float)v[j]*nsc[f] + nsh[f], 0.f);
                    }
                    v = o;
                }
                *(bf16x8*)&As[r][c8*8] = v;
            }
        } else {
            const float* A = (const float*)Av;
            #pragma unroll
            for (int i = 0; i < ROWS/16; ++i){
                int p = tid + i*256;
                int r = p >> 4, c8 = p & 15;
                const float* src = &A[(size_t)(row0 + r)*a_stride + kc + c8*8];
                float4 a0 = *(const float4*)src;
                float4 a1 = *(const float4*)(src + 4);
                bf16x8 o;
                o[0]=(__bf16)a0.x; o[1]=(__bf16)a0.y; o[2]=(__bf16)a0.z; o[3]=(__bf16)a0.w;
                o[4]=(__bf16)a1.x; o[5]=(__bf16)a1.y; o[6]=(__bf16)a1.z; o[7]=(__bf16)a1.w;
                *(bf16x8*)&As[r][c8*8] = o;
            }
        }
        __syncthreads();   // staging complete (vmcnt drained incl. async B)

        #pragma unroll
        for (int ks = 0; ks < 4; ++ks){
            bf16x8 a[RT];
            #pragma unroll
            for (int rt = 0; rt < RT; ++rt)
                a[rt] = *(const bf16x8*)&As[wv*(RT*16) + rt*16 + mrow][ks*32 + q*8];
            #pragma unroll
            for (int ct = 0; ct < 8; ++ct){
                bf16x8 bb = *(const bf16x8*)&Bp[ks*4 + q][ct*16 + mrow][0];
                #pragma unroll
                for (int rt = 0; rt < RT; ++rt)
                    acc[rt][ct] = __builtin_amdgcn_mfma_f32_16x16x32_bf16(a[rt], bb, acc[rt][ct], 0, 0, 0);
            }
        }
    }

    if (STATS){
        if (tid < 128){ statS[tid] = 0.f; statQ[tid] = 0.f; }
        __syncthreads();
    }

    // epilogue: bias + bf16 store + (stats on the rounded values)
    float cs[8] = {0,0,0,0,0,0,0,0}, cq[8] = {0,0,0,0,0,0,0,0};
    #pragma unroll
    for (int ct = 0; ct < 8; ++ct){
        int col = cb0 + ct*16 + mrow;
        float bv = HAS_BIAS ? bias[col] : 0.f;
        #pragma unroll
        for (int rt = 0; rt < RT; ++rt){
            #pragma unroll
            for (int reg = 0; reg < 4; ++reg){
                int row = row0 + wv*(RT*16) + rt*16 + q*4 + reg;
                __bf16 bvv = (__bf16)(acc[rt][ct][reg] + bv);
                outp[(size_t)row*Ctot + col] = bvv;
                if (STATS){ float fv = (float)bvv; cs[ct] += fv; cq[ct] += fv*fv; }
            }
        }
    }
    if (STATS){
        #pragma unroll
        for (int ct = 0; ct < 8; ++ct){
            float s  = cs[ct]; s  += __shfl_xor(s, 16);  s  += __shfl_xor(s, 32);
            float qq = cq[ct]; qq += __shfl_xor(qq, 16); qq += __shfl_xor(qq, 32);
            if (q == 0){
                atomicAdd(&statS[ct*16 + mrow], s);
                atomicAdd(&statQ[ct*16 + mrow], qq);
            }
        }
        __syncthreads();
        if (tid < 128){
            atomicAdd(&outstats[cb0 + tid],        statS[tid]);
            atomicAdd(&outstats[outK + cb0 + tid], statQ[tid]);
        }
    }
}

// ---------------------------------------------------------------------------
// s_i[m] = xlin[m].att_i + e_i[m%N] ; s_j analogous. One wave per row (bf16 in)
// ---------------------------------------------------------------------------
__global__ __launch_bounds__(256) void score_kernel(const __bf16* __restrict__ xl,
                                                    const float2* __restrict__ att_i2,
                                                    const float2* __restrict__ att_j2,
                                                    const float* __restrict__ e_i,
                                                    const float* __restrict__ e_j,
                                                    float* __restrict__ s_i,
                                                    float* __restrict__ s_j){
    int gid = blockIdx.x*256 + threadIdx.x;
    int wid = gid >> 6, lane = gid & 63;
    bf16x2 v = *(const bf16x2*)&xl[(size_t)wid*128 + lane*2];
    float2 ai2 = att_i2[lane], aj2 = att_j2[lane];
    float vx = (float)v[0], vy = (float)v[1];
    float ai = vx*ai2.x + vy*ai2.y;
    float aj = vx*aj2.x + vy*aj2.y;
    for (int off = 32; off; off >>= 1){
        ai += __shfl_down(ai, off);
        aj += __shfl_down(aj, off);
    }
    if (lane == 0){
        int n = wid & 511;
        s_i[wid] = ai + e_i[n];
        s_j[wid] = aj + e_j[n];
    }
}

// ---------------------------------------------------------------------------
// attention softmax + aggregation: one wave per node, shuffle softmax,
// bf16 gathers (4 B/lane). out bf16 (+gnn_bias).
// ---------------------------------------------------------------------------
__global__ __launch_bounds__(256) void agg_kernel(const __bf16* __restrict__ xl,
                                                  const float* __restrict__ s_i,
                                                  const float* __restrict__ s_j,
                                                  const int* __restrict__ topk,
                                                  const float2* __restrict__ gnn_bias2,
                                                  __bf16* __restrict__ aggp){
    int gid  = blockIdx.x*256 + threadIdx.x;
    int m    = gid >> 6, lane = gid & 63;
    int b = m >> 9, i = m & 511;
    int src; bool valid;
    if (lane < KNBR){ int j = topk[i*KNBR + lane]; src = (b << 9) + j; valid = (j != i); }
    else            { src = m; valid = (lane == KNBR); }
    float l = s_i[m] + s_j[src];
    l = (l >= 0.f) ? l : 0.2f*l;                 // leaky_relu 0.2
    l = valid ? l : -1e30f;
    float mx = l;
    #pragma unroll
    for (int mask = 1; mask < 64; mask <<= 1) mx = fmaxf(mx, __shfl_xor(mx, mask));
    float e = valid ? __expf(l - mx) : 0.f;
    float den = e;
    #pragma unroll
    for (int mask = 1; mask < 64; mask <<= 1) den += __shfl_xor(den, mask);
    float alpha = e / den;

    float2 acc = make_float2(0.f, 0.f);
    #pragma unroll 4
    for (int k = 0; k < 33; ++k){
        float a = __shfl(alpha, k);
        int   s = __shfl(src, k);
        bf16x2 v = *(const bf16x2*)&xl[(size_t)s*128 + lane*2];
        acc.x += a*(float)v[0]; acc.y += a*(float)v[1];
    }
    float2 bv = gnn_bias2[lane];
    bf16x2 o;
    o[0] = (__bf16)(acc.x + bv.x);
    o[1] = (__bf16)(acc.y + bv.y);
    *(bf16x2*)&aggp[(size_t)m*128 + lane*2] = o;
}

// ---------------------------------------------------------------------------
// column stats of bf16 [M,128] -> st[0..127]=sum, st[128..255]=sumsq
// ---------------------------------------------------------------------------
__global__ __launch_bounds__(256) void colstats_kernel(const __bf16* __restrict__ X,
                                                       float* __restrict__ st){
    int tid = threadIdx.x;
    int cg = tid & 31, rs = tid >> 5;
    int c0 = cg*4;
    float s[4] = {0,0,0,0}, qq[4] = {0,0,0,0};
    for (int m = blockIdx.x*8 + rs; m < M_ROWS; m += gridDim.x*8){
        bf16x4 v = *(const bf16x4*)&X[(size_t)m*128 + c0];
        #pragma unroll
        for (int j = 0; j < 4; ++j){ float f = (float)v[j]; s[j] += f; qq[j] += f*f; }
    }
    __shared__ float rS[8][128], rQ[8][128];
    #pragma unroll
    for (int j = 0; j < 4; ++j){ rS[rs][c0+j] = s[j]; rQ[rs][c0+j] = qq[j]; }
    __syncthreads();
    if (tid < 128){
        float ts = 0.f, tq = 0.f;
        #pragma unroll
        for (int u = 0; u < 8; ++u){ ts += rS[u][tid]; tq += rQ[u][tid]; }
        atomicAdd(&st[tid],       ts);
        atomicAdd(&st[128 + tid], tq);
    }
}

// ---------------------------------------------------------------------------
// gcn = relu(bn_gnn(agg)); h = gcn * emb[m%N] (bf16 out) + h stats
// ---------------------------------------------------------------------------
__global__ __launch_bounds__(256) void gate_kernel(const __bf16* __restrict__ agg,
                                                   const float* __restrict__ gst,
                                                   const float* __restrict__ g,
                                                   const float* __restrict__ bta,
                                                   const float* __restrict__ emb,
                                                   __bf16* __restrict__ h,
                                                   float* __restrict__ hstats){
    int tid = threadIdx.x;
    int cg = tid & 31, rs = tid >> 5;
    int c0 = cg*4;
    float sc[4], sh[4];
    #pragma unroll
    for (int j = 0; j < 4; ++j){
        float mean = gst[c0+j] * (1.f/32768.f);
        float var  = gst[128 + c0+j] * (1.f/32768.f) - mean*mean;
        sc[j] = g[c0+j] / sqrtf(var + EPSBN);
        sh[j] = bta[c0+j] - mean*sc[j];
    }
    float s[4] = {0,0,0,0}, qq[4] = {0,0,0,0};
    for (int m = blockIdx.x*8 + rs; m < M_ROWS; m += gridDim.x*8){
        bf16x4 v = *(const bf16x4*)&agg[(size_t)m*128 + c0];
        float4 e = *(const float4*)&emb[(size_t)(m & 511)*128 + c0];
        float f0 = fmaxf((float)v[0]*sc[0] + sh[0], 0.f) * e.x;
        float f1 = fmaxf((float)v[1]*sc[1] + sh[1], 0.f) * e.y;
        float f2 = fmaxf((float)v[2]*sc[2] + sh[2], 0.f) * e.z;
        float f3 = fmaxf((float)v[3]*sc[3] + sh[3], 0.f) * e.w;
        bf16x4 o; o[0]=(__bf16)f0; o[1]=(__bf16)f1; o[2]=(__bf16)f2; o[3]=(__bf16)f3;
        *(bf16x4*)&h[(size_t)m*128 + c0] = o;
        float r0=(float)o[0], r1=(float)o[1], r2=(float)o[2], r3=(float)o[3];
        s[0]+=r0; qq[0]+=r0*r0; s[1]+=r1; qq[1]+=r1*r1;
        s[2]+=r2; qq[2]+=r2*r2; s[3]+=r3; qq[3]+=r3*r3;
    }
    __shared__ float rS[8][128], rQ[8][128];
    #pragma unroll
    for (int j = 0; j < 4; ++j){ rS[rs][c0+j] = s[j]; rQ[rs][c0+j] = qq[j]; }
    __syncthreads();
    if (tid < 128){
        float ts = 0.f, tq = 0.f;
        #pragma unroll
        for (int u = 0; u < 8; ++u){ ts += rS[u][tid]; tq += rQ[u][tid]; }
        atomicAdd(&hstats[tid],       ts);
        atomicAdd(&hstats[128 + tid], tq);
    }
}

// ---------------------------------------------------------------------------
// out[m] = relu(bn2(t2[m,:])) . W3 + b3   (one wave per row, bf16 in, f32 out)
// ---------------------------------------------------------------------------
__global__ __launch_bounds__(256) void final_kernel(const __bf16* __restrict__ t2,
                                                    const float* __restrict__ st,
                                                    const float* __restrict__ g,
                                                    const float* __restrict__ bta,
                                                    const float* __restrict__ W3,
                                                    const float* __restrict__ b3,
                                                    float* __restrict__ outp){
    int gid = blockIdx.x*256 + threadIdx.x;
    int wid = gid >> 6, lane = gid & 63;
    int c0 = lane*4;
    bf16x4 v  = *(const bf16x4*)&t2[(size_t)wid*256 + c0];
    float4 w3 = *(const float4*)&W3[c0];
    float4 gg = *(const float4*)&g[c0];
    float4 bb = *(const float4*)&bta[c0];
    float4 sm = *(const float4*)&st[c0];
    float4 sq = *(const float4*)&st[256 + c0];
    float accv = 0.f;
    {
        float mean, var, val;
        mean = sm.x*(1.f/32768.f); var = sq.x*(1.f/32768.f) - mean*mean;
        val = ((float)v[0]-mean)*(gg.x/sqrtf(var+EPSBN)) + bb.x; accv += fmaxf(val,0.f)*w3.x;
        mean = sm.y*(1.f/32768.f); var = sq.y*(1.f/32768.f) - mean*mean;
        val = ((float)v[1]-mean)*(gg.y/sqrtf(var+EPSBN)) + bb.y; accv += fmaxf(val,0.f)*w3.y;
        mean = sm.z*(1.f/32768.f); var = sq.z*(1.f/32768.f) - mean*mean;
        val = ((float)v[2]-mean)*(gg.z/sqrtf(var+EPSBN)) + bb.z; accv += fmaxf(val,0.f)*w3.z;
        mean = sm.w*(1.f/32768.f); var = sq.w*(1.f/32768.f) - mean*mean;
        val = ((float)v[3]-mean)*(gg.w/sqrtf(var+EPSBN)) + bb.w; accv += fmaxf(val,0.f)*w3.w;
    }
    for (int off = 32; off; off >>= 1) accv += __shfl_down(accv, off);
    if (lane == 0) outp[wid] = accv + b3[0];
}

// ---------------------------------------------------------------------------
extern "C" void kernel_launch(void* const* d_in, const int* in_sizes, int n_in,
                              void* d_out, int out_size, void* d_ws, size_t ws_size,
                              hipStream_t stream)
{
    (void)in_sizes; (void)n_in; (void)out_size; (void)ws_size;
    const float* data   = (const float*)d_in[0];
    const float* emb    = (const float*)d_in[1];
    const float* lin_W  = (const float*)d_in[2];
    const float* att_i  = (const float*)d_in[3];
    const float* att_j  = (const float*)d_in[4];
    const float* aem_i  = (const float*)d_in[5];
    const float* aem_j  = (const float*)d_in[6];
    const float* gnn_bias = (const float*)d_in[7];
    const float* gnn_g  = (const float*)d_in[8];
    const float* gnn_b  = (const float*)d_in[9];
    const float* bno_g  = (const float*)d_in[10];
    const float* bno_b  = (const float*)d_in[11];
    const float* W1     = (const float*)d_in[12];
    const float* b1     = (const float*)d_in[13];
    const float* bn1_g  = (const float*)d_in[14];
    const float* bn1_b  = (const float*)d_in[15];
    const float* W2     = (const float*)d_in[16];
    const float* b2     = (const float*)d_in[17];
    const float* bn2_g  = (const float*)d_in[18];
    const float* bn2_b  = (const float*)d_in[19];
    const float* W3     = (const float*)d_in[20];
    const float* b3     = (const float*)d_in[21];
    float* outp = (float*)d_out;
    char*  ws   = (char*)d_ws;

    // workspace layout (bytes)
    int*    topk     = (int*)ws;                        // 64 KB
    float*  e_i      = (float*)(ws + 65536);
    float*  e_j      = (float*)(ws + 67584);
    float*  s_i      = (float*)(ws + 69632);            // 128 KB
    float*  s_j      = (float*)(ws + 200704);           // 128 KB
    float*  stats    = (float*)(ws + 331776);           // 1536 floats
    float*  gnnstats = stats;                           // [256]
    float*  hstats   = stats + 256;                     // [256]
    float*  bn1stats = stats + 512;                     // [512]
    float*  bn2stats = stats + 1024;                    // [512]
    __bf16* Wp0      = (__bf16*)(ws + 337920);          // 32 KB
    __bf16* Wp1      = (__bf16*)(ws + 370688);          // 64 KB
    __bf16* Wp2      = (__bf16*)(ws + 436224);          // 128 KB
    __bf16* xlin     = (__bf16*)(ws + 1048576);                    // 8 MB
    __bf16* aggb     = (__bf16*)(ws + 1048576 +   8388608);        // 8 MB
    __bf16* h        = (__bf16*)(ws + 1048576 + 2*8388608);        // 8 MB
    __bf16* t1       = (__bf16*)(ws + 1048576 + 3*8388608);        // 16 MB
    __bf16* t2       = (__bf16*)(ws + 1048576 + 3*8388608 + 16777216); // 16 MB

    zero_stats_kernel<<<1, 256, 0, stream>>>(stats);
    packw_kernel<<<56, 256, 0, stream>>>(lin_W, W1, W2, Wp0, Wp1, Wp2);
    topk_kernel<<<NNODES, 256, 0, stream>>>(emb, topk);
    embscore_kernel<<<NNODES, 128, 0, stream>>>(emb, aem_i, aem_j, e_i, e_j);

    // xlin = data @ lin_W            (fp32 A, no norm)  [512 blocks, RT=1]
    gemm_kernel<false,false,false,false,1><<<dim3(512,1), 256, 0, stream>>>(
        data, 128, 128, nullptr, nullptr, nullptr, Wp0, 128, nullptr, xlin, nullptr, 0);

    score_kernel<<<M_ROWS/4, 256, 0, stream>>>(xlin, (const float2*)att_i,
                                               (const float2*)att_j, e_i, e_j, s_i, s_j);
    agg_kernel<<<M_ROWS/4, 256, 0, stream>>>(xlin, s_i, s_j, topk,
                                             (const float2*)gnn_bias, aggb);
    colstats_kernel<<<256, 256, 0, stream>>>(aggb, gnnstats);
    gate_kernel<<<256, 256, 0, stream>>>(aggb, gnnstats, gnn_g, gnn_b, emb, h, hstats);

    // t1 = relu(bn_out(h)) @ W1 + b1   (+ bn1 stats)  [512 blocks, RT=2]
    gemm_kernel<true,true,true,true,2><<<dim3(256,2), 256, 0, stream>>>(
        h, 128, 128, hstats, bno_g, bno_b, Wp1, 256, b1, t1, bn1stats, 256);

    // t2 = relu(bn1(t1)) @ W2 + b2     (K=256, + bn2 stats)  [512 blocks, RT=2]
    gemm_kernel<true,true,true,true,2><<<dim3(256,2), 256, 0, stream>>>(
        t1, 256, 256, bn1stats, bn1_g, bn1_b, Wp2, 256, b2, t2, bn2stats, 256);

    final_kernel<<<M_ROWS/4, 256, 0, stream>>>(t2, bn2stats, bn2_g, bn2_b, W3, b3, outp);
}

// Round 4
// 259.597 us; speedup vs baseline: 1.8287x; 1.0207x over previous
//
#include <hip/hip_runtime.h>
#include <math.h>

// Problem constants (B=64, N=512, F_IN=D=128, K=32, INTER=256)
#define M_ROWS 32768
#define NNODES 512
#define KNBR   32
#define EPSBN  1e-5f

typedef __bf16 bf16x8 __attribute__((ext_vector_type(8)));
typedef __bf16 bf16x4 __attribute__((ext_vector_type(4)));
typedef __bf16 bf16x2 __attribute__((ext_vector_type(2)));
typedef float  f32x4  __attribute__((ext_vector_type(4)));

#if defined(__has_builtin)
#if __has_builtin(__builtin_amdgcn_global_load_lds)
#define HAVE_GLL 1
#endif
#endif

// async global->LDS 16B: LDS dst must be wave-uniform base + lane*16
__device__ __forceinline__ void async_ld16(void* lds, const void* g){
#ifdef HAVE_GLL
    __builtin_amdgcn_global_load_lds((__attribute__((address_space(1))) void*)(g),
                                     (__attribute__((address_space(3))) void*)(lds),
                                     16, 0, 0);
#else
    *(bf16x8*)lds = *(const bf16x8*)g;
#endif
}

// ---------------------------------------------------------------------------
// setup_kernel: blocks 0..511  -> topk row i (+ e_i/e_j row i by wave 1)
//               blocks 512..567 -> pack lin_W/W1/W2 to bf16 frag order
//               block  568      -> zero BN stats
// ---------------------------------------------------------------------------
__global__ __launch_bounds__(256) void setup_kernel(
    const float* __restrict__ emb,
    const float* __restrict__ aei, const float* __restrict__ aej,
    const float* __restrict__ lin_W, const float* __restrict__ W1,
    const float* __restrict__ W2,
    int* __restrict__ topk, float* __restrict__ e_i, float* __restrict__ e_j,
    __bf16* __restrict__ Wp0, __bf16* __restrict__ Wp1, __bf16* __restrict__ Wp2,
    float* __restrict__ stats)
{
    int bid = blockIdx.x, tid = threadIdx.x;
    if (bid >= 512){
        if (bid == 568){
            for (int i = tid; i < 1536; i += 256) stats[i] = 0.f;
            return;
        }
        // weight packing: Wp[(kg*C + c)*8 + j] = W[(kg*8+j)*C + c]
        int gidx = (bid - 512)*256 + tid;             // 0..14335
        const float* W; __bf16* o; int C, lg;
        if (gidx < 2048)      { W = lin_W; o = Wp0; C = 128; lg = gidx; }
        else if (gidx < 6144) { W = W1;    o = Wp1; C = 256; lg = gidx - 2048; }
        else                  { W = W2;    o = Wp2; C = 256; lg = gidx - 6144; }
        int kg = (C == 128) ? (lg >> 7) : (lg >> 8);
        int c  = lg & (C - 1);
        bf16x8 pk;
        #pragma unroll
        for (int j = 0; j < 8; ++j) pk[j] = (__bf16)W[(size_t)(kg*8 + j)*C + c];
        *(bf16x8*)&o[(size_t)lg*8] = pk;
        return;
    }

    // ---- topk for row i ----
    __shared__ float wi[128];
    __shared__ float cosv[512];
    int i = bid;
    if (tid < 128) wi[tid] = emb[i*128 + tid];
    __syncthreads();
    float ni = 0.f;
    #pragma unroll 8
    for (int d = 0; d < 128; ++d) ni += wi[d]*wi[d];
    float rni = sqrtf(ni);
    for (int jj = tid; jj < 512; jj += 256){
        const float4* wj4 = (const float4*)(emb + jj*128);
        float dot = 0.f, nj = 0.f;
        #pragma unroll 8
        for (int d4 = 0; d4 < 32; ++d4){
            float4 w = wj4[d4];
            dot += wi[4*d4+0]*w.x + wi[4*d4+1]*w.y + wi[4*d4+2]*w.z + wi[4*d4+3]*w.w;
            nj  += w.x*w.x + w.y*w.y + w.z*w.z + w.w*w.w;
        }
        cosv[jj] = dot / (rni * sqrtf(nj));
    }
    __syncthreads();
    if (tid < 64){
        // wave 0: 32 argmax rounds (tie-break: smaller index)
        int lane = tid;
        float v[8];
        #pragma unroll
        for (int jj = 0; jj < 8; ++jj) v[jj] = cosv[lane + 64*jj];
        for (int k = 0; k < KNBR; ++k){
            float bv = v[0]; int bj = 0;
            #pragma unroll
            for (int jj = 1; jj < 8; ++jj) if (v[jj] > bv){ bv = v[jj]; bj = jj; }
            int bi = lane + 64*bj;
            #pragma unroll
            for (int mask = 1; mask < 64; mask <<= 1){
                float ov = __shfl_xor(bv, mask);
                int   oi = __shfl_xor(bi, mask);
                if (ov > bv || (ov == bv && oi < bi)){ bv = ov; bi = oi; }
            }
            if (lane == 0) topk[i*KNBR + k] = bi;
            if ((bi & 63) == lane){
                int jj = bi >> 6;
                #pragma unroll
                for (int j2 = 0; j2 < 8; ++j2) if (j2 == jj) v[j2] = -2e30f;
            }
        }
    } else if (tid < 128){
        // wave 1: e_i[i] = emb[i].aei ; e_j[i] = emb[i].aej
        int lane = tid - 64;
        float ai = wi[lane]*aei[lane] + wi[lane+64]*aei[lane+64];
        float aj = wi[lane]*aej[lane] + wi[lane+64]*aej[lane+64];
        for (int off = 32; off; off >>= 1){
            ai += __shfl_down(ai, off);
            aj += __shfl_down(aj, off);
        }
        if (lane == 0){ e_i[i] = ai; e_j[i] = aj; }
    }
}

// ---------------------------------------------------------------------------
// xlin GEMM (fp32 A, Ctot=128, 64-row tile) with fused score epilogue:
// writes xlin (bf16) and s_i/s_j (fp32, from the un-rounded accumulators).
// ---------------------------------------------------------------------------
__global__ __launch_bounds__(256) void xlin_gemm_kernel(
    const float* __restrict__ A,
    const __bf16* __restrict__ Wp,
    const float* __restrict__ att_i, const float* __restrict__ att_j,
    const float* __restrict__ e_i,   const float* __restrict__ e_j,
    __bf16* __restrict__ outp,
    float* __restrict__ s_i, float* __restrict__ s_j)
{
    __shared__ __align__(16) __bf16 As[64][136];
    __shared__ __align__(16) __bf16 Bp[16][128][8];

    int tid  = threadIdx.x;
    int lane = tid & 63, wv = tid >> 6;
    int mrow = lane & 15, q = lane >> 4;
    int row0 = blockIdx.x * 64;

    f32x4 acc[8];
    #pragma unroll
    for (int ct = 0; ct < 8; ++ct) acc[ct] = (f32x4){0.f,0.f,0.f,0.f};

    // stage B (async, frag-order 16B granules)
    #pragma unroll
    for (int i = 0; i < 8; ++i){
        int p = tid + i*256;
        const __bf16* src = Wp + ((size_t)(p>>7)*128 + (p&127))*8;
        async_ld16((__bf16*)Bp + (size_t)p*8, src);
    }
    // stage A fp32 -> bf16
    #pragma unroll
    for (int i = 0; i < 4; ++i){
        int p = tid + i*256;
        int r = p >> 4, c8 = p & 15;
        const float* src = &A[(size_t)(row0 + r)*128 + c8*8];
        float4 a0 = *(const float4*)src;
        float4 a1 = *(const float4*)(src + 4);
        bf16x8 o;
        o[0]=(__bf16)a0.x; o[1]=(__bf16)a0.y; o[2]=(__bf16)a0.z; o[3]=(__bf16)a0.w;
        o[4]=(__bf16)a1.x; o[5]=(__bf16)a1.y; o[6]=(__bf16)a1.z; o[7]=(__bf16)a1.w;
        *(bf16x8*)&As[r][c8*8] = o;
    }
    __syncthreads();

    #pragma unroll
    for (int ks = 0; ks < 4; ++ks){
        bf16x8 a = *(const bf16x8*)&As[wv*16 + mrow][ks*32 + q*8];
        #pragma unroll
        for (int ct = 0; ct < 8; ++ct){
            bf16x8 bb = *(const bf16x8*)&Bp[ks*4 + q][ct*16 + mrow][0];
            acc[ct] = __builtin_amdgcn_mfma_f32_16x16x32_bf16(a, bb, acc[ct], 0, 0, 0);
        }
    }

    // epilogue: store bf16 + fused attention scores
    float ai[4] = {0,0,0,0}, aj[4] = {0,0,0,0};
    #pragma unroll
    for (int ct = 0; ct < 8; ++ct){
        int col = ct*16 + mrow;
        float wti = att_i[col], wtj = att_j[col];
        #pragma unroll
        for (int reg = 0; reg < 4; ++reg){
            int row = row0 + wv*16 + q*4 + reg;
            float v = acc[ct][reg];
            outp[(size_t)row*128 + col] = (__bf16)v;
            ai[reg] += v*wti; aj[reg] += v*wtj;
        }
    }
    #pragma unroll
    for (int mask = 1; mask < 16; mask <<= 1){
        #pragma unroll
        for (int reg = 0; reg < 4; ++reg){
            ai[reg] += __shfl_xor(ai[reg], mask);
            aj[reg] += __shfl_xor(aj[reg], mask);
        }
    }
    if (mrow == 0){
        #pragma unroll
        for (int reg = 0; reg < 4; ++reg){
            int row = row0 + wv*16 + q*4 + reg;
            int n = row & 511;
            s_i[row] = ai[reg] + e_i[n];
            s_j[row] = aj[reg] + e_j[n];
        }
    }
}

// ---------------------------------------------------------------------------
// bf16 MFMA GEMM (128x128 tile, RT=2): out = act(A) @ W (+bias) + col stats.
// GATE: A-staging = relu(bn_out( relu(bn_gnn(agg)) * emb )), K=128
// else: A-staging = relu(bn1(t1)), K=256
// ---------------------------------------------------------------------------
template<bool GATE>
__global__ __launch_bounds__(256) void gemm2_kernel(
    const __bf16* __restrict__ A, int a_stride, int Ktot,
    const float* __restrict__ st1, const float* __restrict__ g1, const float* __restrict__ b1,
    const float* __restrict__ emb,
    const float* __restrict__ st2, const float* __restrict__ g2, const float* __restrict__ b2,
    const __bf16* __restrict__ Wp, int Ctot,
    const float* __restrict__ bias,
    __bf16* __restrict__ outp,
    float* __restrict__ outstats, int outK)
{
    __shared__ __align__(16) __bf16 As[128][136];
    __shared__ __align__(16) __bf16 Bp[16][128][8];
    __shared__ float nsc1[128], nsh1[128], nsc2[128], nsh2[128];
    __shared__ float statS[128], statQ[128];

    int tid  = threadIdx.x;
    int lane = tid & 63, wv = tid >> 6;
    int mrow = lane & 15, q = lane >> 4;
    int cb0  = blockIdx.y * 128;
    int row0 = blockIdx.x * 128;

    f32x4 acc[2][8];
    #pragma unroll
    for (int rt = 0; rt < 2; ++rt)
        #pragma unroll
        for (int ct = 0; ct < 8; ++ct)
            acc[rt][ct] = (f32x4){0.f,0.f,0.f,0.f};

    for (int kc = 0; kc < Ktot; kc += 128){
        if (tid < 128){
            int f = kc + tid;
            float mean = st1[f] * (1.f/32768.f);
            float var  = st1[Ktot + f] * (1.f/32768.f) - mean*mean;
            float sc   = g1[f] / sqrtf(var + EPSBN);
            nsc1[tid] = sc;
            nsh1[tid] = b1[f] - mean*sc;
            if (GATE){
                float mean2 = st2[tid] * (1.f/32768.f);
                float var2  = st2[128 + tid] * (1.f/32768.f) - mean2*mean2;
                float sc2   = g2[tid] / sqrtf(var2 + EPSBN);
                nsc2[tid] = sc2;
                nsh2[tid] = b2[tid] - mean2*sc2;
            }
        }
        __syncthreads();

        // B: async 16B granules into LDS
        int kg0 = kc >> 3;
        #pragma unroll
        for (int i = 0; i < 8; ++i){
            int p = tid + i*256;
            const __bf16* src = Wp + ((size_t)(kg0 + (p>>7))*Ctot + cb0 + (p&127))*8;
            async_ld16((__bf16*)Bp + (size_t)p*8, src);
        }
        // A: through regs with fused activation chain
        #pragma unroll
        for (int i = 0; i < 8; ++i){
            int p = tid + i*256;
            int r = p >> 4, c8 = p & 15;
            bf16x8 v = *(const bf16x8*)&A[(size_t)(row0 + r)*a_stride + kc + c8*8];
            bf16x8 o;
            if (GATE){
                const float* ep = &emb[(size_t)((row0 + r) & 511)*128 + c8*8];
                float4 e0 = *(const float4*)ep;
                float4 e1 = *(const float4*)(ep + 4);
                float ee[8] = {e0.x,e0.y,e0.z,e0.w,e1.x,e1.y,e1.z,e1.w};
                #pragma unroll
                for (int j = 0; j < 8; ++j){
                    int f = c8*8 + j;
                    float hv = fmaxf((float)v[j]*nsc1[f] + nsh1[f], 0.f) * ee[j];
                    o[j] = (__bf16)fmaxf(hv*nsc2[f] + nsh2[f], 0.f);
                }
            } else {
                #pragma unroll
                for (int j = 0; j < 8; ++j){
                    int f = c8*8 + j;
                    o[j] = (__bf16)fmaxf((float)v[j]*nsc1[f] + nsh1[f], 0.f);
                }
            }
            *(bf16x8*)&As[r][c8*8] = o;
        }
        __syncthreads();

        #pragma unroll
        for (int ks = 0; ks < 4; ++ks){
            bf16x8 a0 = *(const bf16x8*)&As[wv*32      + mrow][ks*32 + q*8];
            bf16x8 a1 = *(const bf16x8*)&As[wv*32 + 16 + mrow][ks*32 + q*8];
            #pragma unroll
            for (int ct = 0; ct < 8; ++ct){
                bf16x8 bb = *(const bf16x8*)&Bp[ks*4 + q][ct*16 + mrow][0];
                acc[0][ct] = __builtin_amdgcn_mfma_f32_16x16x32_bf16(a0, bb, acc[0][ct], 0, 0, 0);
                acc[1][ct] = __builtin_amdgcn_mfma_f32_16x16x32_bf16(a1, bb, acc[1][ct], 0, 0, 0);
            }
        }
        __syncthreads();
    }

    if (tid < 128){ statS[tid] = 0.f; statQ[tid] = 0.f; }
    __syncthreads();

    float cs[8] = {0,0,0,0,0,0,0,0}, cq[8] = {0,0,0,0,0,0,0,0};
    #pragma unroll
    for (int ct = 0; ct < 8; ++ct){
        int col = cb0 + ct*16 + mrow;
        float bv = bias[col];
        #pragma unroll
        for (int rt = 0; rt < 2; ++rt){
            #pragma unroll
            for (int reg = 0; reg < 4; ++reg){
                int row = row0 + wv*32 + rt*16 + q*4 + reg;
                __bf16 bvv = (__bf16)(acc[rt][ct][reg] + bv);
                outp[(size_t)row*Ctot + col] = bvv;
                float fv = (float)bvv; cs[ct] += fv; cq[ct] += fv*fv;
            }
        }
    }
    #pragma unroll
    for (int ct = 0; ct < 8; ++ct){
        float s  = cs[ct]; s  += __shfl_xor(s, 16);  s  += __shfl_xor(s, 32);
        float qq = cq[ct]; qq += __shfl_xor(qq, 16); qq += __shfl_xor(qq, 32);
        if (q == 0){
            atomicAdd(&statS[ct*16 + mrow], s);
            atomicAdd(&statQ[ct*16 + mrow], qq);
        }
    }
    __syncthreads();
    if (tid < 128){
        atomicAdd(&outstats[cb0 + tid],        statS[tid]);
        atomicAdd(&outstats[outK + cb0 + tid], statQ[tid]);
    }
}

// ---------------------------------------------------------------------------
// attention softmax + aggregation: one wave per node, shuffle softmax,
// bf16 gathers. out bf16 (+gnn_bias).
// ---------------------------------------------------------------------------
__global__ __launch_bounds__(256) void agg_kernel(const __bf16* __restrict__ xl,
                                                  const float* __restrict__ s_i,
                                                  const float* __restrict__ s_j,
                                                  const int* __restrict__ topk,
                                                  const float2* __restrict__ gnn_bias2,
                                                  __bf16* __restrict__ aggp){
    int gid  = blockIdx.x*256 + threadIdx.x;
    int m    = gid >> 6, lane = gid & 63;
    int b = m >> 9, i = m & 511;
    int src; bool valid;
    if (lane < KNBR){ int j = topk[i*KNBR + lane]; src = (b << 9) + j; valid = (j != i); }
    else            { src = m; valid = (lane == KNBR); }
    float l = s_i[m] + s_j[src];
    l = (l >= 0.f) ? l : 0.2f*l;                 // leaky_relu 0.2
    l = valid ? l : -1e30f;
    float mx = l;
    #pragma unroll
    for (int mask = 1; mask < 64; mask <<= 1) mx = fmaxf(mx, __shfl_xor(mx, mask));
    float e = valid ? __expf(l - mx) : 0.f;
    float den = e;
    #pragma unroll
    for (int mask = 1; mask < 64; mask <<= 1) den += __shfl_xor(den, mask);
    float alpha = e / den;

    float2 acc = make_float2(0.f, 0.f);
    #pragma unroll 4
    for (int k = 0; k < 33; ++k){
        float a = __shfl(alpha, k);
        int   s = __shfl(src, k);
        bf16x2 v = *(const bf16x2*)&xl[(size_t)s*128 + lane*2];
        acc.x += a*(float)v[0]; acc.y += a*(float)v[1];
    }
    float2 bv = gnn_bias2[lane];
    bf16x2 o;
    o[0] = (__bf16)(acc.x + bv.x);
    o[1] = (__bf16)(acc.y + bv.y);
    *(bf16x2*)&aggp[(size_t)m*128 + lane*2] = o;
}

// ---------------------------------------------------------------------------
// column stats of bf16 [M,128] -> st[0..127]=sum, st[128..255]=sumsq
// ---------------------------------------------------------------------------
__global__ __launch_bounds__(256) void colstats_kernel(const __bf16* __restrict__ X,
                                                       float* __restrict__ st){
    int tid = threadIdx.x;
    int cg = tid & 31, rs = tid >> 5;
    int c0 = cg*4;
    float s[4] = {0,0,0,0}, qq[4] = {0,0,0,0};
    for (int m = blockIdx.x*8 + rs; m < M_ROWS; m += gridDim.x*8){
        bf16x4 v = *(const bf16x4*)&X[(size_t)m*128 + c0];
        #pragma unroll
        for (int j = 0; j < 4; ++j){ float f = (float)v[j]; s[j] += f; qq[j] += f*f; }
    }
    __shared__ float rS[8][128], rQ[8][128];
    #pragma unroll
    for (int j = 0; j < 4; ++j){ rS[rs][c0+j] = s[j]; rQ[rs][c0+j] = qq[j]; }
    __syncthreads();
    if (tid < 128){
        float ts = 0.f, tq = 0.f;
        #pragma unroll
        for (int u = 0; u < 8; ++u){ ts += rS[u][tid]; tq += rQ[u][tid]; }
        atomicAdd(&st[tid],       ts);
        atomicAdd(&st[128 + tid], tq);
    }
}

// ---------------------------------------------------------------------------
// hstats: h = relu(bn_gnn(agg))*emb computed on the fly (NOT stored);
// accumulate column sum/sumsq of h into hstats.
// ---------------------------------------------------------------------------
__global__ __launch_bounds__(256) void hstats_kernel(const __bf16* __restrict__ agg,
                                                     const float* __restrict__ gst,
                                                     const float* __restrict__ g,
                                                     const float* __restrict__ bta,
                                                     const float* __restrict__ emb,
                                                     float* __restrict__ hstats){
    int tid = threadIdx.x;
    int cg = tid & 31, rs = tid >> 5;
    int c0 = cg*4;
    float sc[4], sh[4];
    #pragma unroll
    for (int j = 0; j < 4; ++j){
        float mean = gst[c0+j] * (1.f/32768.f);
        float var  = gst[128 + c0+j] * (1.f/32768.f) - mean*mean;
        sc[j] = g[c0+j] / sqrtf(var + EPSBN);
        sh[j] = bta[c0+j] - mean*sc[j];
    }
    float s[4] = {0,0,0,0}, qq[4] = {0,0,0,0};
    for (int m = blockIdx.x*8 + rs; m < M_ROWS; m += gridDim.x*8){
        bf16x4 v = *(const bf16x4*)&agg[(size_t)m*128 + c0];
        float4 e = *(const float4*)&emb[(size_t)(m & 511)*128 + c0];
        float f0 = fmaxf((float)v[0]*sc[0] + sh[0], 0.f) * e.x;
        float f1 = fmaxf((float)v[1]*sc[1] + sh[1], 0.f) * e.y;
        float f2 = fmaxf((float)v[2]*sc[2] + sh[2], 0.f) * e.z;
        float f3 = fmaxf((float)v[3]*sc[3] + sh[3], 0.f) * e.w;
        s[0]+=f0; qq[0]+=f0*f0; s[1]+=f1; qq[1]+=f1*f1;
        s[2]+=f2; qq[2]+=f2*f2; s[3]+=f3; qq[3]+=f3*f3;
    }
    __shared__ float rS[8][128], rQ[8][128];
    #pragma unroll
    for (int j = 0; j < 4; ++j){ rS[rs][c0+j] = s[j]; rQ[rs][c0+j] = qq[j]; }
    __syncthreads();
    if (tid < 128){
        float ts = 0.f, tq = 0.f;
        #pragma unroll
        for (int u = 0; u < 8; ++u){ ts += rS[u][tid]; tq += rQ[u][tid]; }
        atomicAdd(&hstats[tid],       ts);
        atomicAdd(&hstats[128 + tid], tq);
    }
}

// ---------------------------------------------------------------------------
// out[m] = relu(bn2(t2[m,:])) . W3 + b3   (one wave per row, bf16 in, f32 out)
// ---------------------------------------------------------------------------
__global__ __launch_bounds__(256) void final_kernel(const __bf16* __restrict__ t2,
                                                    const float* __restrict__ st,
                                                    const float* __restrict__ g,
                                                    const float* __restrict__ bta,
                                                    const float* __restrict__ W3,
                                                    const float* __restrict__ b3,
                                                    float* __restrict__ outp){
    int gid = blockIdx.x*256 + threadIdx.x;
    int wid = gid >> 6, lane = gid & 63;
    int c0 = lane*4;
    bf16x4 v  = *(const bf16x4*)&t2[(size_t)wid*256 + c0];
    float4 w3 = *(const float4*)&W3[c0];
    float4 gg = *(const float4*)&g[c0];
    float4 bb = *(const float4*)&bta[c0];
    float4 sm = *(const float4*)&st[c0];
    float4 sq = *(const float4*)&st[256 + c0];
    float accv = 0.f;
    {
        float mean, var, val;
        mean = sm.x*(1.f/32768.f); var = sq.x*(1.f/32768.f) - mean*mean;
        val = ((float)v[0]-mean)*(gg.x/sqrtf(var+EPSBN)) + bb.x; accv += fmaxf(val,0.f)*w3.x;
        mean = sm.y*(1.f/32768.f); var = sq.y*(1.f/32768.f) - mean*mean;
        val = ((float)v[1]-mean)*(gg.y/sqrtf(var+EPSBN)) + bb.y; accv += fmaxf(val,0.f)*w3.y;
        mean = sm.z*(1.f/32768.f); var = sq.z*(1.f/32768.f) - mean*mean;
        val = ((float)v[2]-mean)*(gg.z/sqrtf(var+EPSBN)) + bb.z; accv += fmaxf(val,0.f)*w3.z;
        mean = sm.w*(1.f/32768.f); var = sq.w*(1.f/32768.f) - mean*mean;
        val = ((float)v[3]-mean)*(gg.w/sqrtf(var+EPSBN)) + bb.w; accv += fmaxf(val,0.f)*w3.w;
    }
    for (int off = 32; off; off >>= 1) accv += __shfl_down(accv, off);
    if (lane == 0) outp[wid] = accv + b3[0];
}

// ---------------------------------------------------------------------------
extern "C" void kernel_launch(void* const* d_in, const int* in_sizes, int n_in,
                              void* d_out, int out_size, void* d_ws, size_t ws_size,
                              hipStream_t stream)
{
    (void)in_sizes; (void)n_in; (void)out_size; (void)ws_size;
    const float* data   = (const float*)d_in[0];
    const float* emb    = (const float*)d_in[1];
    const float* lin_W  = (const float*)d_in[2];
    const float* att_i  = (const float*)d_in[3];
    const float* att_j  = (const float*)d_in[4];
    const float* aem_i  = (const float*)d_in[5];
    const float* aem_j  = (const float*)d_in[6];
    const float* gnn_bias = (const float*)d_in[7];
    const float* gnn_g  = (const float*)d_in[8];
    const float* gnn_b  = (const float*)d_in[9];
    const float* bno_g  = (const float*)d_in[10];
    const float* bno_b  = (const float*)d_in[11];
    const float* W1     = (const float*)d_in[12];
    const float* b1     = (const float*)d_in[13];
    const float* bn1_g  = (const float*)d_in[14];
    const float* bn1_b  = (const float*)d_in[15];
    const float* W2     = (const float*)d_in[16];
    const float* b2     = (const float*)d_in[17];
    const float* bn2_g  = (const float*)d_in[18];
    const float* bn2_b  = (const float*)d_in[19];
    const float* W3     = (const float*)d_in[20];
    const float* b3     = (const float*)d_in[21];
    float* outp = (float*)d_out;
    char*  ws   = (char*)d_ws;

    // workspace layout (bytes)
    int*    topk     = (int*)ws;                        // 64 KB
    float*  e_i      = (float*)(ws + 65536);
    float*  e_j      = (float*)(ws + 67584);
    float*  s_i      = (float*)(ws + 69632);            // 128 KB
    float*  s_j      = (float*)(ws + 200704);           // 128 KB
    float*  stats    = (float*)(ws + 331776);           // 1536 floats
    float*  gnnstats = stats;                           // [256]
    float*  hstats   = stats + 256;                     // [256]
    float*  bn1stats = stats + 512;                     // [512]
    float*  bn2stats = stats + 1024;                    // [512]
    __bf16* Wp0      = (__bf16*)(ws + 337920);          // 32 KB
    __bf16* Wp1      = (__bf16*)(ws + 370688);          // 64 KB
    __bf16* Wp2      = (__bf16*)(ws + 436224);          // 128 KB
    __bf16* xlin     = (__bf16*)(ws + 1048576);                    // 8 MB
    __bf16* aggb     = (__bf16*)(ws + 1048576 +   8388608);        // 8 MB
    __bf16* t1       = (__bf16*)(ws + 1048576 + 2*8388608);        // 16 MB
    __bf16* t2       = (__bf16*)(ws + 1048576 + 2*8388608 + 16777216); // 16 MB

    // setup: topk + e_i/e_j + weight pack + stats zero (one launch)
    setup_kernel<<<569, 256, 0, stream>>>(emb, aem_i, aem_j, lin_W, W1, W2,
                                          topk, e_i, e_j, Wp0, Wp1, Wp2, stats);

    // xlin = data @ lin_W  (+ fused s_i/s_j epilogue)
    xlin_gemm_kernel<<<512, 256, 0, stream>>>(data, Wp0, att_i, att_j, e_i, e_j,
                                              xlin, s_i, s_j);

    agg_kernel<<<M_ROWS/4, 256, 0, stream>>>(xlin, s_i, s_j, topk,
                                             (const float2*)gnn_bias, aggb);
    colstats_kernel<<<256, 256, 0, stream>>>(aggb, gnnstats);
    hstats_kernel<<<256, 256, 0, stream>>>(aggb, gnnstats, gnn_g, gnn_b, emb, hstats);

    // t1 = relu(bn_out( relu(bn_gnn(agg))*emb )) @ W1 + b1   (+ bn1 stats)
    gemm2_kernel<true><<<dim3(256,2), 256, 0, stream>>>(
        aggb, 128, 128, gnnstats, gnn_g, gnn_b, emb, hstats, bno_g, bno_b,
        Wp1, 256, b1, t1, bn1stats, 256);

    // t2 = relu(bn1(t1)) @ W2 + b2   (K=256, + bn2 stats)
    gemm2_kernel<false><<<dim3(256,2), 256, 0, stream>>>(
        t1, 256, 256, bn1stats, bn1_g, bn1_b, nullptr, nullptr, nullptr, nullptr,
        Wp2, 256, b2, t2, bn2stats, 256);

    final_kernel<<<M_ROWS/4, 256, 0, stream>>>(t2, bn2stats, bn2_g, bn2_b, W3, b3, outp);
}